// Round 12
// baseline (200.637 us; speedup 1.0000x reference)
//
#include <hip/hip_runtime.h>
#include <hip/hip_bf16.h>

// Problem constants
#define DM     768
#define HEADS  12
#define DK     64
#define SQ     2048
#define BATCH  2
#define ROWS   4096   // BATCH * SQ
#define KTILES 24     // DM / 32

typedef __attribute__((ext_vector_type(4))) float f32x4;
typedef __bf16 bf16x8 __attribute__((ext_vector_type(8)));
typedef unsigned short u16x8 __attribute__((ext_vector_type(8)));
typedef unsigned short u16x4 __attribute__((ext_vector_type(4)));

#define QSCALE 0.180336880f   // (1/sqrt(64)) * log2(e): scores feed exp2

static __device__ __forceinline__ unsigned short f2bf(float f) {
    union { float f; unsigned u; } v; v.f = f;
    unsigned u = v.u;
    unsigned lsb = (u >> 16) & 1u;
    u += 0x7fffu + lsb;              // round-to-nearest-even
    return (unsigned short)(u >> 16);
}

static __device__ __forceinline__ unsigned pack_bf16(float a, float b) {
    __hip_bfloat162 h = __float22bfloat162_rn(make_float2(a, b));  // v_cvt_pk_bf16_f32
    unsigned u;
    __builtin_memcpy(&u, &h, 4);
    return u;
}

// Raw v_exp_f32 (2^x). Scores are bounded well inside [-126,128].
static __device__ __forceinline__ float fexp2(float x) {
#if __has_builtin(__builtin_amdgcn_exp2f)
    return __builtin_amdgcn_exp2f(x);
#else
    return exp2f(x);
#endif
}

static __device__ __forceinline__ bf16x8 load_bf16x8(const unsigned short* p) {
    u16x8 u = *(const u16x8*)p;      // 16B load
    return __builtin_bit_cast(bf16x8, u);
}

// ---------- merged prep: fp32->bf16 fragment-linear converts ------------------
// Blocks 0..767: activations via LDS transpose (coalesced reads).
// Blocks 768..1919: weights (gather reads, 64B-coalesced per 16-lane group).
#define LROW 776   // 768 + 8 pad (u16)
__global__ __launch_bounds__(256) void prep(const float* __restrict__ X0,
                                            const float* __restrict__ X1,
                                            const float* __restrict__ X2,
                                            const float* __restrict__ W0,
                                            const float* __restrict__ W1,
                                            const float* __restrict__ W2,
                                            const float* __restrict__ W3,
                                            unsigned short* __restrict__ A0,
                                            unsigned short* __restrict__ A1,
                                            unsigned short* __restrict__ A2,
                                            unsigned short* __restrict__ F0,
                                            unsigned short* __restrict__ F1,
                                            unsigned short* __restrict__ F2,
                                            unsigned short* __restrict__ F3) {
    __shared__ __align__(16) unsigned short lds[16 * LROW];   // 24.8KB
    int blk = blockIdx.x;
    int tid = threadIdx.x;
    if (blk < 768) {
        int z  = blk >> 8;           // 3 x 256
        int mt = blk & 255;
        const float* X = z == 0 ? X0 : z == 1 ? X1 : X2;
        unsigned short* A = z == 0 ? A0 : z == 1 ? A1 : A2;
        const float* src = X + (size_t)mt * 16 * DM;
        // Phase 1: coalesced read 16x768 fp32, convert, store LDS [row][col].
#pragma unroll
        for (int i = 0; i < 12; ++i) {
            int fi = tid + i * 256;          // float4 index 0..3071
            int row = fi / 192;              // 192 float4 per row
            int c4  = fi - row * 192;
            float4 v = *(const float4*)(src + (size_t)fi * 4);
            u16x4 o;
            o[0] = f2bf(v.x); o[1] = f2bf(v.y); o[2] = f2bf(v.z); o[3] = f2bf(v.w);
            *(u16x4*)(&lds[row * LROW + c4 * 4]) = o;
        }
        __syncthreads();
        // Phase 2: fragment-linear output, coalesced 16B stores.
        unsigned short* out = A + (size_t)mt * KTILES * 512;
#pragma unroll
        for (int c = 0; c < 6; ++c) {
            int idx  = tid + c * 256;        // ks*64 + lane, 0..1535
            int ks   = idx >> 6;
            int lane = idx & 63;
            int r15  = lane & 15;
            int qd   = lane >> 4;
            u16x8 v = *(const u16x8*)(&lds[r15 * LROW + ks * 32 + qd * 8]);
            *(u16x8*)(out + (size_t)idx * 8) = v;
        }
    } else {
        int q  = blk - 768;
        int z  = q / 288;
        int pb = q - z * 288;
        const float* W = z == 0 ? W0 : z == 1 ? W1 : z == 2 ? W2 : W3;
        unsigned short* F = z == 0 ? F0 : z == 1 ? F1 : z == 2 ? F2 : F3;
        int p = pb * 256 + tid;
        int lane = p & 63;
        int t = (p >> 6) & 3;
        int g = p >> 8;
        int ks = g % KTILES;
        int nb = g / KTILES;
        int n = nb * 64 + t * 16 + (lane & 15);
        int k = ks * 32 + (lane >> 4) * 8;
        u16x8 o;
#pragma unroll
        for (int j = 0; j < 8; ++j) o[j] = f2bf(W[(size_t)(k + j) * DM + n]);
        *(u16x8*)(F + (size_t)p * 8) = o;
    }
}

// ---------------- QKV GEMM v2: barrier-free, LDS-free ------------------------
// The LDS B-staging was pointless the same way flash's K/V staging was (R2->R4):
// B-frags are wave-invariant, tiny (294KB/panel), and L2/L3-resident. Direct
// global loads of the SAME frag-linear bytes delete 12 drain+barrier convoys
// per block and the 32KB LDS (occupancy up). Waves fully independent. A-frags
// register-prefetched one kt ahead (issued before B loads so ~300cy of B-load+
// MFMA hides the A latency). Grid swap retained: blockIdx.x = row-tile -> all
// 12 blocks sharing an A-panel sit on one XCD (IDs differ by 32 == 0 mod 8).
__global__ __launch_bounds__(256) void gemm_qkv(const unsigned short* __restrict__ A0,
                                                const unsigned short* __restrict__ A1,
                                                const unsigned short* __restrict__ A2,
                                                const unsigned short* __restrict__ F0,
                                                const unsigned short* __restrict__ F1,
                                                const unsigned short* __restrict__ F2,
                                                const float* __restrict__ b0,
                                                const float* __restrict__ b1,
                                                const float* __restrict__ b2,
                                                unsigned short* __restrict__ Qo,
                                                unsigned short* __restrict__ Ko,
                                                unsigned short* __restrict__ Vo) {
    int z = blockIdx.z;
    const unsigned short* A = z == 0 ? A0 : z == 1 ? A1 : A2;
    const unsigned short* F = z == 0 ? F0 : z == 1 ? F1 : F2;
    const float* bias        = z == 0 ? b0 : z == 1 ? b1 : b2;

    int w    = threadIdx.x >> 6;
    int lane = threadIdx.x & 63;
    int l15  = lane & 15;
    int quad = lane >> 4;
    int m0 = blockIdx.x * 128 + w * 32;   // row tile from .x (XCD-local A reuse)
    int nb = blockIdx.y;                  // col tile from .y
    int mt0 = m0 >> 4;

    const unsigned short* Ap = A + (size_t)mt0 * KTILES * 512 + lane * 8;
    const unsigned short* Bp = F + (size_t)nb * KTILES * 2048 + lane * 8;

    f32x4 acc[2][4];
#pragma unroll
    for (int i = 0; i < 2; ++i)
#pragma unroll
        for (int t = 0; t < 4; ++t) acc[i][t] = (f32x4){0.f, 0.f, 0.f, 0.f};

    bf16x8 a_cur[2];
#pragma unroll
    for (int i = 0; i < 2; ++i)
        a_cur[i] = load_bf16x8(Ap + (size_t)i * KTILES * 512);

    for (int kt = 0; kt < KTILES; ++kt) {
        bf16x8 a0 = a_cur[0], a1 = a_cur[1];
        if (kt < KTILES - 1) {
#pragma unroll
            for (int i = 0; i < 2; ++i)
                a_cur[i] = load_bf16x8(Ap + ((size_t)i * KTILES + kt + 1) * 512);
        }
#pragma unroll
        for (int t = 0; t < 4; ++t) {
            bf16x8 bb = load_bf16x8(Bp + (size_t)kt * 2048 + t * 512);
            acc[0][t] = __builtin_amdgcn_mfma_f32_16x16x32_bf16(a0, bb, acc[0][t], 0, 0, 0);
            acc[1][t] = __builtin_amdgcn_mfma_f32_16x16x32_bf16(a1, bb, acc[1][t], 0, 0, 0);
        }
    }

    float scale = (z == 0) ? QSCALE : 1.0f;
#pragma unroll
    for (int t = 0; t < 4; ++t) {
        int col = nb * 64 + t * 16 + l15;
        float bv = bias[col];
        int h = col >> 6, d = col & (DK - 1);
#pragma unroll
        for (int i = 0; i < 2; ++i)
#pragma unroll
            for (int r = 0; r < 4; ++r) {
                int row = m0 + i * 16 + quad * 4 + r;
                float v = (acc[i][t][r] + bv) * scale;
                int bb = row >> 11, s = row & (SQ - 1);
                size_t bh = (size_t)(bb * HEADS + h);
                if (z == 0) {
                    Qo[(bh * SQ + s) * DK + d] = f2bf(v);
                } else if (z == 1) {
                    int sc = s & 63;
                    Ko[(bh * (SQ / 64) + (s >> 6)) * 4096 + sc * 64 +
                       (((d >> 3) ^ ((sc >> 1) & 7)) << 3) + (d & 7)] = f2bf(v);
                } else {
                    int sc = s & 63;
                    Vo[(bh * (SQ / 64) + (s >> 6)) * 4096 + d * 64 +
                       (((sc >> 3) ^ ((d >> 1) & 7)) << 3) + (sc & 7)] = f2bf(v);
                }
            }
    }
}

// ---------------- Flash attention v7 (verified 59.2us): direct-global K/V -----
__global__ __launch_bounds__(256) void flash_attn(const unsigned short* __restrict__ Q,
                                                  const unsigned short* __restrict__ Kb,
                                                  const unsigned short* __restrict__ Vb,
                                                  unsigned short* __restrict__ Af) {
    __shared__ __align__(16) unsigned short ldsP[4][32 * 72]; // per-wave P (18KB)
    __shared__ __align__(16) float fO[2][2048];               // parity combine (16KB)
    __shared__ __align__(16) float fL[2][512];                // parity lsum (4KB)

    int w    = threadIdx.x >> 6;
    int lane = threadIdx.x & 63;
    int l15  = lane & 15;
    int quad = lane >> 4;
    int rg   = w >> 1;        // row-group: q-rows rg*32..rg*32+31
    int par  = w & 1;         // chunk parity

    // Bijective XCD-grouping swizzle (768 = 8 XCDs x 96): 3 (b,h) pairs per
    // XCD -> K/V stays L2-resident (verified: FETCH_SIZE 52->9.3 MB).
    int lin  = blockIdx.x;
    int nlin = (lin & 7) * 96 + (lin >> 3);
    int q0   = (nlin & 31) * 64 + rg * 32;
    int h    = (nlin >> 5) % HEADS;
    int b    = nlin / (32 * HEADS);

    size_t bh = (size_t)(b * HEADS + h);
    const unsigned short* Qp = Q  + (bh * SQ + q0) * DK;
    const unsigned short* KB = Kb + bh * (SQ / 64) * 4096;
    const unsigned short* VB = Vb + bh * (SQ / 64) * 4096;

    bf16x8 aq[2][2];
#pragma unroll
    for (int i = 0; i < 2; ++i) {
        aq[i][0] = load_bf16x8(Qp + (i * 16 + l15) * DK + quad * 8);
        aq[i][1] = load_bf16x8(Qp + (i * 16 + l15) * DK + 32 + quad * 8);
    }

    f32x4 o[2][4];
#pragma unroll
    for (int i = 0; i < 2; ++i)
#pragma unroll
        for (int t = 0; t < 4; ++t) o[i][t] = (f32x4){0.f, 0.f, 0.f, 0.f};
    float lsum[2][4] = {{0.f,0.f,0.f,0.f},{0.f,0.f,0.f,0.f}};

    unsigned short* Pw = &ldsP[w][0];

    // Fragment offsets within a linear 64-key chunk (halfs); swizzle matches
    // the gemm_qkv writer.
    int koff[4][2], voff[4][2];
#pragma unroll
    for (int t = 0; t < 4; ++t) {
        int pr = (t >> 1) * 32 + 2 * l15 + (t & 1);
        int sw = l15 & 7;
        koff[t][0] = pr * 64 + (((quad)     ^ sw) << 3);
        koff[t][1] = pr * 64 + (((4 + quad) ^ sw) << 3);
        int d = t * 16 + l15;
        int swv = (l15 >> 1) & 7;
        voff[t][0] = d * 64 + (((quad)     ^ swv) << 3);
        voff[t][1] = d * 64 + (((4 + quad) ^ swv) << 3);
    }

    u16x8 kreg[8], vreg[8];
#define LOADK(n) do { \
        const unsigned short* kc_ = KB + (size_t)(n) * 4096; \
        _Pragma("unroll") \
        for (int t = 0; t < 4; ++t) { \
            kreg[2 * t]     = *(const u16x8*)(kc_ + koff[t][0]); \
            kreg[2 * t + 1] = *(const u16x8*)(kc_ + koff[t][1]); \
        } \
    } while (0)
#define LOADV(n) do { \
        const unsigned short* vc_ = VB + (size_t)(n) * 4096; \
        _Pragma("unroll") \
        for (int t = 0; t < 4; ++t) { \
            vreg[2 * t]     = *(const u16x8*)(vc_ + voff[t][0]); \
            vreg[2 * t + 1] = *(const u16x8*)(vc_ + voff[t][1]); \
        } \
    } while (0)

    LOADK(par);
    LOADV(par);

    for (int s = 0; s < 16; ++s) {
        f32x4 sc[2][4];
#pragma unroll
        for (int i = 0; i < 2; ++i)
#pragma unroll
            for (int t = 0; t < 4; ++t) sc[i][t] = (f32x4){0.f, 0.f, 0.f, 0.f};

        __builtin_amdgcn_s_setprio(1);
#pragma unroll
        for (int t = 0; t < 4; ++t) {
            bf16x8 k0 = __builtin_bit_cast(bf16x8, kreg[2 * t]);
            bf16x8 k1 = __builtin_bit_cast(bf16x8, kreg[2 * t + 1]);
#pragma unroll
            for (int i = 0; i < 2; ++i) {
                sc[i][t] = __builtin_amdgcn_mfma_f32_16x16x32_bf16(aq[i][0], k0, sc[i][t], 0, 0, 0);
                sc[i][t] = __builtin_amdgcn_mfma_f32_16x16x32_bf16(aq[i][1], k1, sc[i][t], 0, 0, 0);
            }
        }
        __builtin_amdgcn_s_setprio(0);

        // kreg consumed -> issue next chunk's K loads (land during exp2+PV)
        if (s < 15) LOADK(2 * s + 2 + par);

        // exp2 + packed P write (cols: sub*32 + 2*l15 + {0,1})
#pragma unroll
        for (int i = 0; i < 2; ++i)
#pragma unroll
            for (int sub = 0; sub < 2; ++sub)
#pragma unroll
                for (int r = 0; r < 4; ++r) {
                    float e0 = fexp2(sc[i][2 * sub][r]);
                    float e1 = fexp2(sc[i][2 * sub + 1][r]);
                    lsum[i][r] += e0 + e1;
                    *(unsigned*)(Pw + (i * 16 + quad * 4 + r) * 72 + sub * 32 + l15 * 2)
                        = pack_bf16(e0, e1);
                }

        bf16x8 pf[2][2];
#pragma unroll
        for (int i = 0; i < 2; ++i) {
            pf[i][0] = load_bf16x8(Pw + (i * 16 + l15) * 72 + quad * 8);
            pf[i][1] = load_bf16x8(Pw + (i * 16 + l15) * 72 + 32 + quad * 8);
        }

        __builtin_amdgcn_s_setprio(1);
#pragma unroll
        for (int t = 0; t < 4; ++t) {
            bf16x8 v0 = __builtin_bit_cast(bf16x8, vreg[2 * t]);
            bf16x8 v1 = __builtin_bit_cast(bf16x8, vreg[2 * t + 1]);
#pragma unroll
            for (int i = 0; i < 2; ++i) {
                o[i][t] = __builtin_amdgcn_mfma_f32_16x16x32_bf16(pf[i][0], v0, o[i][t], 0, 0, 0);
                o[i][t] = __builtin_amdgcn_mfma_f32_16x16x32_bf16(pf[i][1], v1, o[i][t], 0, 0, 0);
            }
        }
        __builtin_amdgcn_s_setprio(0);

        // vreg consumed -> issue next chunk's V loads
        if (s < 15) LOADV(2 * s + 2 + par);
    }
#undef LOADK
#undef LOADV

    // -------- parity combine (unnormalized partials are additive) --------
    if (par == 1) {
#pragma unroll
        for (int i = 0; i < 2; ++i)
#pragma unroll
            for (int r = 0; r < 4; ++r) {
                int rowin = i * 16 + quad * 4 + r;
#pragma unroll
                for (int t = 0; t < 4; ++t)
                    fO[rg][rowin * 64 + t * 16 + l15] = o[i][t][r];
                fL[rg][rowin * 16 + l15] = lsum[i][r];
            }
    }
    __syncthreads();
    if (par == 0) {
#pragma unroll
        for (int i = 0; i < 2; ++i)
#pragma unroll
            for (int r = 0; r < 4; ++r) {
                int rowin = i * 16 + quad * 4 + r;
                float l = lsum[i][r] + fL[rg][rowin * 16 + l15];
                l += __shfl_xor(l, 1);
                l += __shfl_xor(l, 2);
                l += __shfl_xor(l, 4);
                l += __shfl_xor(l, 8);
                float inv = 1.0f / l;
                int R  = b * SQ + q0 + rowin;
                int mt = R >> 4;
#pragma unroll
                for (int t = 0; t < 4; ++t) {
                    float val = o[i][t][r] + fO[rg][rowin * 64 + t * 16 + l15];
                    int ks    = h * 2 + (t >> 1);
                    int quadp = ((t & 1) << 1) + (l15 >> 3);
                    int j     = l15 & 7;
                    Af[(size_t)(mt * KTILES + ks) * 512 +
                       (size_t)((quadp << 4) + (rowin & 15)) * 8 + j] = f2bf(val * inv);
                }
            }
    }
}

// ---------------- Output projection v2: barrier-free, LDS-free ----------------
// Same direct-global B structure as gemm_qkv v2. Grid swap retained.
__global__ __launch_bounds__(256) void gemm_out(const unsigned short* __restrict__ Af,
                                                const unsigned short* __restrict__ Ff,
                                                const float* __restrict__ bias,
                                                float* __restrict__ out) {
    int w    = threadIdx.x >> 6;
    int lane = threadIdx.x & 63;
    int l15  = lane & 15;
    int quad = lane >> 4;
    int m0 = blockIdx.x * 128 + w * 32;   // row tile from .x (XCD-local A reuse)
    int nb = blockIdx.y;                  // col tile from .y
    int mt0 = m0 >> 4;

    const unsigned short* Ap = Af + (size_t)mt0 * KTILES * 512 + lane * 8;
    const unsigned short* Bp = Ff + (size_t)nb * KTILES * 2048 + lane * 8;

    f32x4 acc[2][4];
#pragma unroll
    for (int i = 0; i < 2; ++i)
#pragma unroll
        for (int t = 0; t < 4; ++t) acc[i][t] = (f32x4){0.f, 0.f, 0.f, 0.f};

    bf16x8 a_cur[2];
#pragma unroll
    for (int i = 0; i < 2; ++i)
        a_cur[i] = load_bf16x8(Ap + (size_t)i * KTILES * 512);

    for (int kt = 0; kt < KTILES; ++kt) {
        bf16x8 a0 = a_cur[0], a1 = a_cur[1];
        if (kt < KTILES - 1) {
#pragma unroll
            for (int i = 0; i < 2; ++i)
                a_cur[i] = load_bf16x8(Ap + ((size_t)i * KTILES + kt + 1) * 512);
        }
#pragma unroll
        for (int t = 0; t < 4; ++t) {
            bf16x8 bb = load_bf16x8(Bp + (size_t)kt * 2048 + t * 512);
            acc[0][t] = __builtin_amdgcn_mfma_f32_16x16x32_bf16(a0, bb, acc[0][t], 0, 0, 0);
            acc[1][t] = __builtin_amdgcn_mfma_f32_16x16x32_bf16(a1, bb, acc[1][t], 0, 0, 0);
        }
    }

#pragma unroll
    for (int t = 0; t < 4; ++t) {
        int col = nb * 64 + t * 16 + l15;
        float bv = bias[col];
#pragma unroll
        for (int i = 0; i < 2; ++i)
#pragma unroll
            for (int r = 0; r < 4; ++r) {
                int row = m0 + i * 16 + quad * 4 + r;
                out[(size_t)row * DM + col] = acc[i][t][r] + bv;
            }
    }
}

extern "C" void kernel_launch(void* const* d_in, const int* in_sizes, int n_in,
                              void* d_out, int out_size, void* d_ws, size_t ws_size,
                              hipStream_t stream) {
    const float* query = (const float*)d_in[0];
    const float* key   = (const float*)d_in[1];
    const float* value = (const float*)d_in[2];
    const float* Wq = (const float*)d_in[3];  const float* bq = (const float*)d_in[4];
    const float* Wk = (const float*)d_in[5];  const float* bk = (const float*)d_in[6];
    const float* Wv = (const float*)d_in[7];  const float* bv = (const float*)d_in[8];
    const float* Wo = (const float*)d_in[9];  const float* bo = (const float*)d_in[10];

    const size_t NX = (size_t)ROWS * DM;        // 3,145,728
    const size_t NW = (size_t)DM * DM;          // 589,824
    unsigned short* Xq  = (unsigned short*)d_ws;   // frag(query); reused as frag(attn-out)
    unsigned short* Xk  = Xq  + NX;
    unsigned short* Xv  = Xk  + NX;
    unsigned short* Qb  = Xv  + NX;                // [B,H,S,DK]
    unsigned short* Kb  = Qb  + NX;                // blocked+swizzled
    unsigned short* Vt  = Kb  + NX;                // blocked+swizzled
    unsigned short* Wtq = Vt  + NX;
    unsigned short* Wtk = Wtq + NW;
    unsigned short* Wtv = Wtk + NW;
    unsigned short* Wto = Wtv + NW;

    prep<<<dim3(1920, 1, 1), 256, 0, stream>>>(
        query, key, value, Wq, Wk, Wv, Wo,
        Xq, Xk, Xv, Wtq, Wtk, Wtv, Wto);

    gemm_qkv<<<dim3(ROWS / 128, DM / 64, 3), 256, 0, stream>>>(
        Xq, Xk, Xv, Wtq, Wtk, Wtv, bq, bk, bv, Qb, Kb, Vt);

    flash_attn<<<dim3((SQ / 64) * HEADS * BATCH, 1, 1), 256, 0, stream>>>(Qb, Kb, Vt, Xq);

    gemm_out<<<dim3(ROWS / 128, DM / 64), 256, 0, stream>>>(Xq, Wto, bo, (float*)d_out);
}

// Round 13
// 184.205 us; speedup vs baseline: 1.0892x; 1.0892x over previous
//
#include <hip/hip_runtime.h>
#include <hip/hip_bf16.h>

// Problem constants
#define DM     768
#define HEADS  12
#define DK     64
#define SQ     2048
#define BATCH  2
#define ROWS   4096   // BATCH * SQ
#define KTILES 24     // DM / 32

typedef __attribute__((ext_vector_type(4))) float f32x4;
typedef __bf16 bf16x8 __attribute__((ext_vector_type(8)));
typedef unsigned short u16x8 __attribute__((ext_vector_type(8)));
typedef unsigned short u16x4 __attribute__((ext_vector_type(4)));

#define QSCALE 0.180336880f   // (1/sqrt(64)) * log2(e): scores feed exp2

static __device__ __forceinline__ unsigned short f2bf(float f) {
    union { float f; unsigned u; } v; v.f = f;
    unsigned u = v.u;
    unsigned lsb = (u >> 16) & 1u;
    u += 0x7fffu + lsb;              // round-to-nearest-even
    return (unsigned short)(u >> 16);
}

static __device__ __forceinline__ unsigned pack_bf16(float a, float b) {
    __hip_bfloat162 h = __float22bfloat162_rn(make_float2(a, b));  // v_cvt_pk_bf16_f32
    unsigned u;
    __builtin_memcpy(&u, &h, 4);
    return u;
}

// Raw v_exp_f32 (2^x). Scores are bounded well inside [-126,128].
static __device__ __forceinline__ float fexp2(float x) {
#if __has_builtin(__builtin_amdgcn_exp2f)
    return __builtin_amdgcn_exp2f(x);
#else
    return exp2f(x);
#endif
}

static __device__ __forceinline__ bf16x8 load_bf16x8(const unsigned short* p) {
    u16x8 u = *(const u16x8*)p;      // 16B load
    return __builtin_bit_cast(bf16x8, u);
}

// Async global->LDS DMA: 64 lanes x 16B; LDS dest = uniform base + lane*16.
static __device__ __forceinline__ void gld_lds16(const unsigned short* g, unsigned short* l) {
    __builtin_amdgcn_global_load_lds((const __attribute__((address_space(1))) void*)g,
                                     (__attribute__((address_space(3))) void*)l,
                                     16, 0, 0);
}

// Explicit DMA drain (gemm kernels). __syncthreads() alone does NOT guarantee
// each wave's global_load_lds has landed before the barrier when the data is
// consumed only by sibling waves. Force the drain.
static __device__ __forceinline__ void drain_dma() {
    asm volatile("s_waitcnt vmcnt(0)" ::: "memory");
}

// ---------- merged prep: fp32->bf16 fragment-linear converts ------------------
// Blocks 0..767: activations via LDS transpose (coalesced reads).
// Blocks 768..1919: weights (gather reads, 64B-coalesced per 16-lane group).
#define LROW 776   // 768 + 8 pad (u16)
__global__ __launch_bounds__(256) void prep(const float* __restrict__ X0,
                                            const float* __restrict__ X1,
                                            const float* __restrict__ X2,
                                            const float* __restrict__ W0,
                                            const float* __restrict__ W1,
                                            const float* __restrict__ W2,
                                            const float* __restrict__ W3,
                                            unsigned short* __restrict__ A0,
                                            unsigned short* __restrict__ A1,
                                            unsigned short* __restrict__ A2,
                                            unsigned short* __restrict__ F0,
                                            unsigned short* __restrict__ F1,
                                            unsigned short* __restrict__ F2,
                                            unsigned short* __restrict__ F3) {
    __shared__ __align__(16) unsigned short lds[16 * LROW];   // 24.8KB
    int blk = blockIdx.x;
    int tid = threadIdx.x;
    if (blk < 768) {
        int z  = blk >> 8;           // 3 x 256
        int mt = blk & 255;
        const float* X = z == 0 ? X0 : z == 1 ? X1 : X2;
        unsigned short* A = z == 0 ? A0 : z == 1 ? A1 : A2;
        const float* src = X + (size_t)mt * 16 * DM;
        // Phase 1: coalesced read 16x768 fp32, convert, store LDS [row][col].
#pragma unroll
        for (int i = 0; i < 12; ++i) {
            int fi = tid + i * 256;          // float4 index 0..3071
            int row = fi / 192;              // 192 float4 per row
            int c4  = fi - row * 192;
            float4 v = *(const float4*)(src + (size_t)fi * 4);
            u16x4 o;
            o[0] = f2bf(v.x); o[1] = f2bf(v.y); o[2] = f2bf(v.z); o[3] = f2bf(v.w);
            *(u16x4*)(&lds[row * LROW + c4 * 4]) = o;
        }
        __syncthreads();
        // Phase 2: fragment-linear output, coalesced 16B stores.
        unsigned short* out = A + (size_t)mt * KTILES * 512;
#pragma unroll
        for (int c = 0; c < 6; ++c) {
            int idx  = tid + c * 256;        // ks*64 + lane, 0..1535
            int ks   = idx >> 6;
            int lane = idx & 63;
            int r15  = lane & 15;
            int qd   = lane >> 4;
            u16x8 v = *(const u16x8*)(&lds[r15 * LROW + ks * 32 + qd * 8]);
            *(u16x8*)(out + (size_t)idx * 8) = v;
        }
    } else {
        int q  = blk - 768;
        int z  = q / 288;
        int pb = q - z * 288;
        const float* W = z == 0 ? W0 : z == 1 ? W1 : z == 2 ? W2 : W3;
        unsigned short* F = z == 0 ? F0 : z == 1 ? F1 : z == 2 ? F2 : F3;
        int p = pb * 256 + tid;
        int lane = p & 63;
        int t = (p >> 6) & 3;
        int g = p >> 8;
        int ks = g % KTILES;
        int nb = g / KTILES;
        int n = nb * 64 + t * 16 + (lane & 15);
        int k = ks * 32 + (lane >> 4) * 8;
        u16x8 o;
#pragma unroll
        for (int j = 0; j < 8; ++j) o[j] = f2bf(W[(size_t)(k + j) * DM + n]);
        *(u16x8*)(F + (size_t)p * 8) = o;
    }
}

// ---------------- QKV GEMM (R10-v1, verified): staged LDS, XCD-local grid -----
// R12 proved the staged version beats direct-global B (wave-shared operand:
// staging amortizes; direct loads exposed 24 serialized L2 round-trips/wave).
__global__ __launch_bounds__(256) void gemm_qkv(const unsigned short* __restrict__ A0,
                                                const unsigned short* __restrict__ A1,
                                                const unsigned short* __restrict__ A2,
                                                const unsigned short* __restrict__ F0,
                                                const unsigned short* __restrict__ F1,
                                                const unsigned short* __restrict__ F2,
                                                const float* __restrict__ b0,
                                                const float* __restrict__ b1,
                                                const float* __restrict__ b2,
                                                unsigned short* __restrict__ Qo,
                                                unsigned short* __restrict__ Ko,
                                                unsigned short* __restrict__ Vo) {
    __shared__ __align__(16) unsigned short ldsB[2][8192];   // 16KB x2

    int z = blockIdx.z;
    const unsigned short* A = z == 0 ? A0 : z == 1 ? A1 : A2;
    const unsigned short* F = z == 0 ? F0 : z == 1 ? F1 : F2;
    const float* bias        = z == 0 ? b0 : z == 1 ? b1 : b2;

    int w    = threadIdx.x >> 6;
    int lane = threadIdx.x & 63;
    int l15  = lane & 15;
    int quad = lane >> 4;
    int m0 = blockIdx.x * 128 + w * 32;   // row tile from .x (XCD-local A reuse)
    int nb = blockIdx.y;                  // col tile from .y
    int mt0 = m0 >> 4;

    const unsigned short* Ap = A + (size_t)mt0 * KTILES * 512 + lane * 8;
    const unsigned short* Bsrc = F + (size_t)nb * KTILES * 4 * 512 + w * 2048 + lane * 8;
    unsigned short* Bdst = &ldsB[0][w * 2048];

    f32x4 acc[2][4];
#pragma unroll
    for (int i = 0; i < 2; ++i)
#pragma unroll
        for (int t = 0; t < 4; ++t) acc[i][t] = (f32x4){0.f, 0.f, 0.f, 0.f};

#define BSTAGE(buf, c) do { \
        _Pragma("unroll") \
        for (int j = 0; j < 4; ++j) \
            gld_lds16(Bsrc + (size_t)(c) * 8192 + j * 512, Bdst + (buf) * 8192 + j * 512); \
    } while (0)

    BSTAGE(0, 0);

    // A-register prefetch: load iteration 0's fragments up front.
    bf16x8 a_cur[2][4];
#pragma unroll
    for (int k4 = 0; k4 < 4; ++k4)
#pragma unroll
        for (int i = 0; i < 2; ++i)
            a_cur[i][k4] = load_bf16x8(Ap + ((size_t)i * KTILES + k4) * 512);

    for (int c = 0; c < 6; ++c) {
        drain_dma();          // publish this wave's BSTAGE(c) (and land A prefetch)
        __syncthreads();
        if (c < 5) BSTAGE((c + 1) & 1, c + 1);
        const unsigned short* Bl = &ldsB[c & 1][0];
#pragma unroll
        for (int k4 = 0; k4 < 4; ++k4) {
#pragma unroll
            for (int t = 0; t < 4; ++t) {
                bf16x8 bb = load_bf16x8(Bl + (k4 * 4 + t) * 512 + lane * 8);
#pragma unroll
                for (int i = 0; i < 2; ++i)
                    acc[i][t] = __builtin_amdgcn_mfma_f32_16x16x32_bf16(a_cur[i][k4], bb, acc[i][t], 0, 0, 0);
            }
            // In-place prefetch of next iteration's A fragments (WAR, no extra VGPR).
            if (c < 5) {
#pragma unroll
                for (int i = 0; i < 2; ++i)
                    a_cur[i][k4] = load_bf16x8(Ap + ((size_t)i * KTILES + (c + 1) * 4 + k4) * 512);
            }
        }
    }
#undef BSTAGE

    float scale = (z == 0) ? QSCALE : 1.0f;
#pragma unroll
    for (int t = 0; t < 4; ++t) {
        int col = nb * 64 + t * 16 + l15;
        float bv = bias[col];
        int h = col >> 6, d = col & (DK - 1);
#pragma unroll
        for (int i = 0; i < 2; ++i)
#pragma unroll
            for (int r = 0; r < 4; ++r) {
                int row = m0 + i * 16 + quad * 4 + r;
                float v = (acc[i][t][r] + bv) * scale;
                int bb = row >> 11, s = row & (SQ - 1);
                size_t bh = (size_t)(bb * HEADS + h);
                if (z == 0) {
                    Qo[(bh * SQ + s) * DK + d] = f2bf(v);
                } else if (z == 1) {
                    int sc = s & 63;
                    Ko[(bh * (SQ / 64) + (s >> 6)) * 4096 + sc * 64 +
                       (((d >> 3) ^ ((sc >> 1) & 7)) << 3) + (d & 7)] = f2bf(v);
                } else {
                    int sc = s & 63;
                    Vo[(bh * (SQ / 64) + (s >> 6)) * 4096 + d * 64 +
                       (((sc >> 3) ^ ((d >> 1) & 7)) << 3) + (sc & 7)] = f2bf(v);
                }
            }
    }
}

// ---------------- Flash attention v9: per-i P-pipeline split ------------------
// v7 dataflow (verified 59.2us) with the softmax->PV chain split per i:
// {exp2[i]+Pwrite[i] -> pf[i] read -> PV[i]} so pf[0]'s read waits on only 8
// LDS writes (not 16) and i=1's register-only exp2 hoists under pf[0]'s read
// latency; PV[0] MFMAs overlap write[1]. Pure reorder — addresses/values
// byte-identical to v7.
__global__ __launch_bounds__(256) void flash_attn(const unsigned short* __restrict__ Q,
                                                  const unsigned short* __restrict__ Kb,
                                                  const unsigned short* __restrict__ Vb,
                                                  unsigned short* __restrict__ Af) {
    __shared__ __align__(16) unsigned short ldsP[4][32 * 72]; // per-wave P (18KB)
    __shared__ __align__(16) float fO[2][2048];               // parity combine (16KB)
    __shared__ __align__(16) float fL[2][512];                // parity lsum (4KB)

    int w    = threadIdx.x >> 6;
    int lane = threadIdx.x & 63;
    int l15  = lane & 15;
    int quad = lane >> 4;
    int rg   = w >> 1;        // row-group: q-rows rg*32..rg*32+31
    int par  = w & 1;         // chunk parity

    // Bijective XCD-grouping swizzle (768 = 8 XCDs x 96): 3 (b,h) pairs per
    // XCD -> K/V stays L2-resident (verified: FETCH_SIZE 52->9.3 MB).
    int lin  = blockIdx.x;
    int nlin = (lin & 7) * 96 + (lin >> 3);
    int q0   = (nlin & 31) * 64 + rg * 32;
    int h    = (nlin >> 5) % HEADS;
    int b    = nlin / (32 * HEADS);

    size_t bh = (size_t)(b * HEADS + h);
    const unsigned short* Qp = Q  + (bh * SQ + q0) * DK;
    const unsigned short* KB = Kb + bh * (SQ / 64) * 4096;
    const unsigned short* VB = Vb + bh * (SQ / 64) * 4096;

    bf16x8 aq[2][2];
#pragma unroll
    for (int i = 0; i < 2; ++i) {
        aq[i][0] = load_bf16x8(Qp + (i * 16 + l15) * DK + quad * 8);
        aq[i][1] = load_bf16x8(Qp + (i * 16 + l15) * DK + 32 + quad * 8);
    }

    f32x4 o[2][4];
#pragma unroll
    for (int i = 0; i < 2; ++i)
#pragma unroll
        for (int t = 0; t < 4; ++t) o[i][t] = (f32x4){0.f, 0.f, 0.f, 0.f};
    float lsum[2][4] = {{0.f,0.f,0.f,0.f},{0.f,0.f,0.f,0.f}};

    unsigned short* Pw = &ldsP[w][0];

    // Fragment offsets within a linear 64-key chunk (halfs); swizzle matches
    // the gemm_qkv writer.
    int koff[4][2], voff[4][2];
#pragma unroll
    for (int t = 0; t < 4; ++t) {
        int pr = (t >> 1) * 32 + 2 * l15 + (t & 1);
        int sw = l15 & 7;
        koff[t][0] = pr * 64 + (((quad)     ^ sw) << 3);
        koff[t][1] = pr * 64 + (((4 + quad) ^ sw) << 3);
        int d = t * 16 + l15;
        int swv = (l15 >> 1) & 7;
        voff[t][0] = d * 64 + (((quad)     ^ swv) << 3);
        voff[t][1] = d * 64 + (((4 + quad) ^ swv) << 3);
    }

    u16x8 kreg[8], vreg[8];
#define LOADK(n) do { \
        const unsigned short* kc_ = KB + (size_t)(n) * 4096; \
        _Pragma("unroll") \
        for (int t = 0; t < 4; ++t) { \
            kreg[2 * t]     = *(const u16x8*)(kc_ + koff[t][0]); \
            kreg[2 * t + 1] = *(const u16x8*)(kc_ + koff[t][1]); \
        } \
    } while (0)
#define LOADV(n) do { \
        const unsigned short* vc_ = VB + (size_t)(n) * 4096; \
        _Pragma("unroll") \
        for (int t = 0; t < 4; ++t) { \
            vreg[2 * t]     = *(const u16x8*)(vc_ + voff[t][0]); \
            vreg[2 * t + 1] = *(const u16x8*)(vc_ + voff[t][1]); \
        } \
    } while (0)

    LOADK(par);
    LOADV(par);

    for (int s = 0; s < 16; ++s) {
        f32x4 sc[2][4];
#pragma unroll
        for (int i = 0; i < 2; ++i)
#pragma unroll
            for (int t = 0; t < 4; ++t) sc[i][t] = (f32x4){0.f, 0.f, 0.f, 0.f};

        __builtin_amdgcn_s_setprio(1);
#pragma unroll
        for (int t = 0; t < 4; ++t) {
            bf16x8 k0 = __builtin_bit_cast(bf16x8, kreg[2 * t]);
            bf16x8 k1 = __builtin_bit_cast(bf16x8, kreg[2 * t + 1]);
#pragma unroll
            for (int i = 0; i < 2; ++i) {
                sc[i][t] = __builtin_amdgcn_mfma_f32_16x16x32_bf16(aq[i][0], k0, sc[i][t], 0, 0, 0);
                sc[i][t] = __builtin_amdgcn_mfma_f32_16x16x32_bf16(aq[i][1], k1, sc[i][t], 0, 0, 0);
            }
        }
        __builtin_amdgcn_s_setprio(0);

        // kreg consumed -> issue next chunk's K loads (land during exp2+PV)
        if (s < 15) LOADK(2 * s + 2 + par);

        // Per-i softmax->PV pipeline: pf[i] read waits on only this i's 8
        // writes; the other i's exp2 (register-only) overlaps the read latency.
#pragma unroll
        for (int i = 0; i < 2; ++i) {
#pragma unroll
            for (int sub = 0; sub < 2; ++sub)
#pragma unroll
                for (int r = 0; r < 4; ++r) {
                    float e0 = fexp2(sc[i][2 * sub][r]);
                    float e1 = fexp2(sc[i][2 * sub + 1][r]);
                    lsum[i][r] += e0 + e1;
                    *(unsigned*)(Pw + (i * 16 + quad * 4 + r) * 72 + sub * 32 + l15 * 2)
                        = pack_bf16(e0, e1);
                }

            bf16x8 pf0 = load_bf16x8(Pw + (i * 16 + l15) * 72 + quad * 8);
            bf16x8 pf1 = load_bf16x8(Pw + (i * 16 + l15) * 72 + 32 + quad * 8);

            __builtin_amdgcn_s_setprio(1);
#pragma unroll
            for (int t = 0; t < 4; ++t) {
                bf16x8 v0 = __builtin_bit_cast(bf16x8, vreg[2 * t]);
                bf16x8 v1 = __builtin_bit_cast(bf16x8, vreg[2 * t + 1]);
                o[i][t] = __builtin_amdgcn_mfma_f32_16x16x32_bf16(pf0, v0, o[i][t], 0, 0, 0);
                o[i][t] = __builtin_amdgcn_mfma_f32_16x16x32_bf16(pf1, v1, o[i][t], 0, 0, 0);
            }
            __builtin_amdgcn_s_setprio(0);
        }

        // vreg consumed -> issue next chunk's V loads
        if (s < 15) LOADV(2 * s + 2 + par);
    }
#undef LOADK
#undef LOADV

    // -------- parity combine (unnormalized partials are additive) --------
    if (par == 1) {
#pragma unroll
        for (int i = 0; i < 2; ++i)
#pragma unroll
            for (int r = 0; r < 4; ++r) {
                int rowin = i * 16 + quad * 4 + r;
#pragma unroll
                for (int t = 0; t < 4; ++t)
                    fO[rg][rowin * 64 + t * 16 + l15] = o[i][t][r];
                fL[rg][rowin * 16 + l15] = lsum[i][r];
            }
    }
    __syncthreads();
    if (par == 0) {
#pragma unroll
        for (int i = 0; i < 2; ++i)
#pragma unroll
            for (int r = 0; r < 4; ++r) {
                int rowin = i * 16 + quad * 4 + r;
                float l = lsum[i][r] + fL[rg][rowin * 16 + l15];
                l += __shfl_xor(l, 1);
                l += __shfl_xor(l, 2);
                l += __shfl_xor(l, 4);
                l += __shfl_xor(l, 8);
                float inv = 1.0f / l;
                int R  = b * SQ + q0 + rowin;
                int mt = R >> 4;
#pragma unroll
                for (int t = 0; t < 4; ++t) {
                    float val = o[i][t][r] + fO[rg][rowin * 64 + t * 16 + l15];
                    int ks    = h * 2 + (t >> 1);
                    int quadp = ((t & 1) << 1) + (l15 >> 3);
                    int j     = l15 & 7;
                    Af[(size_t)(mt * KTILES + ks) * 512 +
                       (size_t)((quadp << 4) + (rowin & 15)) * 8 + j] = f2bf(val * inv);
                }
            }
    }
}

// ---------------- Output projection (R10-v1, verified): staged LDS -----------
__global__ __launch_bounds__(256) void gemm_out(const unsigned short* __restrict__ Af,
                                                const unsigned short* __restrict__ Ff,
                                                const float* __restrict__ bias,
                                                float* __restrict__ out) {
    __shared__ __align__(16) unsigned short ldsB[2][8192];   // 16KB x2

    int w    = threadIdx.x >> 6;
    int lane = threadIdx.x & 63;
    int l15  = lane & 15;
    int quad = lane >> 4;
    int m0 = blockIdx.x * 128 + w * 32;   // row tile from .x (XCD-local A reuse)
    int nb = blockIdx.y;                  // col tile from .y
    int mt0 = m0 >> 4;

    const unsigned short* Ap = Af + (size_t)mt0 * KTILES * 512 + lane * 8;
    const unsigned short* Bsrc = Ff + (size_t)nb * KTILES * 4 * 512 + w * 2048 + lane * 8;
    unsigned short* Bdst = &ldsB[0][w * 2048];

    f32x4 acc[2][4];
#pragma unroll
    for (int i = 0; i < 2; ++i)
#pragma unroll
        for (int t = 0; t < 4; ++t) acc[i][t] = (f32x4){0.f, 0.f, 0.f, 0.f};

#define BSTAGE(buf, c) do { \
        _Pragma("unroll") \
        for (int j = 0; j < 4; ++j) \
            gld_lds16(Bsrc + (size_t)(c) * 8192 + j * 512, Bdst + (buf) * 8192 + j * 512); \
    } while (0)

    BSTAGE(0, 0);

    bf16x8 a_cur[2][4];
#pragma unroll
    for (int k4 = 0; k4 < 4; ++k4)
#pragma unroll
        for (int i = 0; i < 2; ++i)
            a_cur[i][k4] = load_bf16x8(Ap + ((size_t)i * KTILES + k4) * 512);

    for (int c = 0; c < 6; ++c) {
        drain_dma();          // publish this wave's BSTAGE(c) (and land A prefetch)
        __syncthreads();
        if (c < 5) BSTAGE((c + 1) & 1, c + 1);
        const unsigned short* Bl = &ldsB[c & 1][0];
#pragma unroll
        for (int k4 = 0; k4 < 4; ++k4) {
#pragma unroll
            for (int t = 0; t < 4; ++t) {
                bf16x8 bb = load_bf16x8(Bl + (k4 * 4 + t) * 512 + lane * 8);
#pragma unroll
                for (int i = 0; i < 2; ++i)
                    acc[i][t] = __builtin_amdgcn_mfma_f32_16x16x32_bf16(a_cur[i][k4], bb, acc[i][t], 0, 0, 0);
            }
            if (c < 5) {
#pragma unroll
                for (int i = 0; i < 2; ++i)
                    a_cur[i][k4] = load_bf16x8(Ap + ((size_t)i * KTILES + (c + 1) * 4 + k4) * 512);
            }
        }
    }
#undef BSTAGE

#pragma unroll
    for (int t = 0; t < 4; ++t) {
        int col = nb * 64 + t * 16 + l15;
        float bv = bias[col];
#pragma unroll
        for (int i = 0; i < 2; ++i)
#pragma unroll
            for (int r = 0; r < 4; ++r) {
                int row = m0 + i * 16 + quad * 4 + r;
                out[(size_t)row * DM + col] = acc[i][t][r] + bv;
            }
    }
}

extern "C" void kernel_launch(void* const* d_in, const int* in_sizes, int n_in,
                              void* d_out, int out_size, void* d_ws, size_t ws_size,
                              hipStream_t stream) {
    const float* query = (const float*)d_in[0];
    const float* key   = (const float*)d_in[1];
    const float* value = (const float*)d_in[2];
    const float* Wq = (const float*)d_in[3];  const float* bq = (const float*)d_in[4];
    const float* Wk = (const float*)d_in[5];  const float* bk = (const float*)d_in[6];
    const float* Wv = (const float*)d_in[7];  const float* bv = (const float*)d_in[8];
    const float* Wo = (const float*)d_in[9];  const float* bo = (const float*)d_in[10];

    const size_t NX = (size_t)ROWS * DM;        // 3,145,728
    const size_t NW = (size_t)DM * DM;          // 589,824
    unsigned short* Xq  = (unsigned short*)d_ws;   // frag(query); reused as frag(attn-out)
    unsigned short* Xk  = Xq  + NX;
    unsigned short* Xv  = Xk  + NX;
    unsigned short* Qb  = Xv  + NX;                // [B,H,S,DK]
    unsigned short* Kb  = Qb  + NX;                // blocked+swizzled
    unsigned short* Vt  = Kb  + NX;                // blocked+swizzled
    unsigned short* Wtq = Vt  + NX;
    unsigned short* Wtk = Wtq + NW;
    unsigned short* Wtv = Wtk + NW;
    unsigned short* Wto = Wtv + NW;

    prep<<<dim3(1920, 1, 1), 256, 0, stream>>>(
        query, key, value, Wq, Wk, Wv, Wo,
        Xq, Xk, Xv, Wtq, Wtk, Wtv, Wto);

    gemm_qkv<<<dim3(ROWS / 128, DM / 64, 3), 256, 0, stream>>>(
        Xq, Xk, Xv, Wtq, Wtk, Wtv, bq, bk, bv, Qb, Kb, Vt);

    flash_attn<<<dim3((SQ / 64) * HEADS * BATCH, 1, 1), 256, 0, stream>>>(Qb, Kb, Vt, Xq);

    gemm_out<<<dim3(ROWS / 128, DM / 64), 256, 0, stream>>>(Xq, Wto, bo, (float*)d_out);
}